// Round 2
// baseline (433.567 us; speedup 1.0000x reference)
//
#include <hip/hip_runtime.h>
#include <math.h>

#define N_TOK 32768
#define K_CODES 4096
#define DIM 512
#define COMMIT 0.25f
#define NCAND 8
#define NSPLIT 2
#define SPLIT_CODES (K_CODES / NSPLIT)   // 2048
#define NITER (SPLIT_CODES / 256)        // 8 col-iterations of 256 codes
#define BIAS 0.125f

typedef short s16x8 __attribute__((ext_vector_type(8)));
typedef float f32x4 __attribute__((ext_vector_type(4)));
typedef unsigned int uint32;
typedef unsigned long long u64;
typedef unsigned short u16;

__device__ __forceinline__ u16 f2bf(float f) {
    uint32 b = __float_as_uint(f);
    return (u16)((b + 0x7FFFu + ((b >> 16) & 1u)) >> 16);
}

// global -> LDS direct DMA, 16B per lane. LDS dest must be wave-uniform;
// HW writes lds + lane*16. Source is per-lane (pre-swizzled).
__device__ __forceinline__ void gload16(const u16* g, u16* l) {
    __builtin_amdgcn_global_load_lds(
        (const __attribute__((address_space(1))) void*)g,
        (__attribute__((address_space(3))) void*)l,
        16, 0, 0);
}

// ---------------------------------------------------------------------------
// fp32 -> bf16 (RNE) bulk convert.
// ---------------------------------------------------------------------------
__global__ __launch_bounds__(256) void tobf16_kernel(const float* __restrict__ src,
                                                     u16* __restrict__ dst, int n4) {
    int i = blockIdx.x * 256 + threadIdx.x;
    int stride = gridDim.x * 256;
    for (; i < n4; i += stride) {
        float4 v = ((const float4*)src)[i];
        ushort4 o;
        o.x = f2bf(v.x); o.y = f2bf(v.y); o.z = f2bf(v.z); o.w = f2bf(v.w);
        ((ushort4*)dst)[i] = o;
    }
}

// ---------------------------------------------------------------------------
// numpy-exact fp32 row sum of squares (pairwise algorithm) — R3-verified.
// ---------------------------------------------------------------------------
__global__ __launch_bounds__(256) void rowsq_np_kernel(const float* __restrict__ a,
                                                       float* __restrict__ out,
                                                       int nrows) {
    #pragma clang fp contract(off)
    const int gw   = (blockIdx.x * 256 + threadIdx.x) >> 6;
    const int lane = threadIdx.x & 63;
    const int row  = gw * 8 + (lane >> 3);
    const int j    = lane & 7;
    if (row >= nrows) return;
    const float* p = a + (size_t)row * DIM;
    float blk[4];
    #pragma unroll
    for (int b = 0; b < 4; ++b) {
        const float* q = p + b * 128;
        float v = q[j];
        float r = v * v;
        for (int i = 8; i < 128; i += 8) { float u = q[i + j]; r += u * u; }
        float s1 = r  + __shfl_xor(r, 1);
        float s2 = s1 + __shfl_xor(s1, 2);
        float s3 = s2 + __shfl_xor(s2, 4);
        blk[b] = s3;
    }
    float res = (blk[0] + blk[1]) + (blk[2] + blk[3]);
    if (j == 0) out[row] = res;
}

// ---------------------------------------------------------------------------
// MFMA bf16 screen. Block: 512 thr = 8 waves, tile 128 tok x 256 codes/iter.
// Wave tile 64 tok x 64 codes (4x4 grid of 16x16x32 MFMA). K staged BK=64,
// double-buffered LDS, XOR-swizzled 128B rows (16B quantum q -> q^(row&7)).
// Staging via global_load_lds (linear LDS dest, PRE-SWIZZLED per-lane global
// source: src quantum = (lane&7)^(lane>>3) — same involution the reads use).
// Per-(lane,token) top-2 packed keys; final full merge in LDS -> top-6/split.
// ---------------------------------------------------------------------------
__global__ __launch_bounds__(512, 2) void screen_kernel(const u16* __restrict__ xb,
                                                        const u16* __restrict__ wb,
                                                        const float* __restrict__ w2f,
                                                        u64* __restrict__ candPart) {
    __shared__ __attribute__((aligned(16))) u16 POOL[49152];  // 96 KiB
    // Xs buffers: 128 rows x 64 elems (128 B rows): [0]=0, [1]=8192 (u16 units)
    // Ws buffers: 256 rows x 64 elems: [0]=16384, [1]=32768

    const int tid  = threadIdx.x;
    const int wv   = tid >> 6;
    const int wt   = wv >> 2;          // token half (0/1)
    const int wc   = wv & 3;           // code column (0..3)
    const int lane = tid & 63;
    const int quad = lane >> 4;
    const int n15  = lane & 15;
    const int m0   = blockIdx.x * 128;
    const int sbase = blockIdx.y * SPLIT_CODES;

    // ---- DMA staging geometry -------------------------------------------
    // Each global_load_lds instr: 64 lanes x 16B = 1KB = 8 rows x 8 quanta.
    // lane -> row_lsb = lane>>3, phys quantum qs = lane&7.
    // Content at (row, qs) must be logical quantum qs^(row&7); row&7 == lane>>3
    // for all our row bases (multiples of 8), so src quantum = (lane&7)^(lane>>3).
    const int l8  = lane >> 3;
    const int qsw = (lane & 7) ^ l8;       // pre-swizzled source quantum

    // X: wave wv covers rows [wv*16, wv*16+16), 2 instrs of 8 rows.
    const u16* xg0 = xb + (size_t)(m0 + wv * 16 + 0 + l8) * DIM + qsw * 8;
    const u16* xg1 = xb + (size_t)(m0 + wv * 16 + 8 + l8) * DIM + qsw * 8;
    // W: wave wv covers rows [wv*32, wv*32+32), 4 instrs of 8 rows.
    // Per-it base: wit = wb + nbase*DIM + qsw*8; instr j adds (wv*32+j*8+l8)*DIM.
    const size_t wofs0 = (size_t)(wv * 32 + 0  + l8) * DIM;
    const size_t wofs1 = (size_t)(wv * 32 + 8  + l8) * DIM;
    const size_t wofs2 = (size_t)(wv * 32 + 16 + l8) * DIM;
    const size_t wofs3 = (size_t)(wv * 32 + 24 + l8) * DIM;

    // wave-uniform LDS bases (u16 units); buffer b, instr j adds j*512
    u16* ldsx0 = &POOL[0     + wv * 1024];
    u16* ldsx1 = &POOL[8192  + wv * 1024];
    u16* ldsw0 = &POOL[16384 + wv * 2048];
    u16* ldsw1 = &POOL[32768 + wv * 2048];

    uint32 r1[16], r2[16];
    #pragma unroll
    for (int i = 0; i < 16; ++i) { r1[i] = 0xFFFFFFFFu; r2[i] = 0xFFFFFFFFu; }

    const u16* wit = wb + (size_t)sbase * DIM + qsw * 8;  // += 256*DIM per it

    // prologue: stage it=0 chunk 0 into buffer 0
    {
        gload16(xg0, ldsx0);
        gload16(xg0 + 512, ldsx0 + 512);  // NOTE: replaced below — see loop form
    }
    // (the prologue above is rewritten properly just after; kept minimal)
    // Correct prologue:
    // -- erase effect of placeholder by restaging identical data is harmless;
    //    both instructions above already staged rows wv*16..+8 (xg0) twice is
    //    NOT what we want, so do the real prologue now:
    gload16(xg1, ldsx0 + 512);
    gload16(wit + wofs0, ldsw0);
    gload16(wit + wofs1, ldsw0 + 512);
    gload16(wit + wofs2, ldsw0 + 1024);
    gload16(wit + wofs3, ldsw0 + 1536);
    __syncthreads();

    for (int it = 0; it < NITER; ++it) {
        const int nbase = sbase + it * 256;

        float w2pb[4];
        #pragma unroll
        for (int c = 0; c < 4; ++c) w2pb[c] = w2f[nbase + wc * 64 + c * 16 + n15] + BIAS;

        f32x4 acc[4][4];
        #pragma unroll
        for (int i = 0; i < 4; ++i)
            #pragma unroll
            for (int c = 0; c < 4; ++c) acc[i][c] = (f32x4){0.f, 0.f, 0.f, 0.f};

        for (int kc = 0; kc < 8; ++kc) {
            // prefetch: chunks kc+1 of this column, or chunk 0 of next column
            if (kc < 7) {
                const int nb = (kc + 1) & 1;
                u16* lx = nb ? ldsx1 : ldsx0;
                u16* lw = nb ? ldsw1 : ldsw0;
                const int ko = (kc + 1) * 64;
                gload16(xg0 + ko, lx);
                gload16(xg1 + ko, lx + 512);
                gload16(wit + wofs0 + ko, lw);
                gload16(wit + wofs1 + ko, lw + 512);
                gload16(wit + wofs2 + ko, lw + 1024);
                gload16(wit + wofs3 + ko, lw + 1536);
            } else if (it < NITER - 1) {
                const u16* wn = wit + (size_t)256 * DIM;
                gload16(xg0, ldsx0);
                gload16(xg1, ldsx0 + 512);
                gload16(wn + wofs0, ldsw0);
                gload16(wn + wofs1, ldsw0 + 512);
                gload16(wn + wofs2, ldsw0 + 1024);
                gload16(wn + wofs3, ldsw0 + 1536);
            }

            const u16* X = &POOL[(kc & 1) * 8192];
            const u16* W = &POOL[16384 + (kc & 1) * 16384];
            #pragma unroll
            for (int s = 0; s < 2; ++s) {
                const int lq = s * 4 + quad;
                s16x8 af[4], bf[4];
                #pragma unroll
                for (int i = 0; i < 4; ++i) {
                    const int tr = wt * 64 + i * 16 + n15;
                    af[i] = *(const s16x8*)&X[tr * 64 + (lq ^ (tr & 7)) * 8];
                }
                #pragma unroll
                for (int c = 0; c < 4; ++c) {
                    const int cr = wc * 64 + c * 16 + n15;
                    bf[c] = *(const s16x8*)&W[cr * 64 + (lq ^ (cr & 7)) * 8];
                }
                #pragma unroll
                for (int i = 0; i < 4; ++i)
                    #pragma unroll
                    for (int c = 0; c < 4; ++c)
                        acc[i][c] = __builtin_amdgcn_mfma_f32_16x16x32_bf16(af[i], bf[c], acc[i][c], 0, 0, 0);
            }
            __syncthreads();   // compiler emits vmcnt(0) drain -> staged data visible
        }

        // fold this 256-code column into running top-2 per (lane, token-slot)
        #pragma unroll
        for (int i = 0; i < 4; ++i)
            #pragma unroll
            for (int r = 0; r < 4; ++r) {
                const int ti = i * 4 + r;
                #pragma unroll
                for (int c = 0; c < 4; ++c) {
                    float s = fmaf(-2.0f, acc[i][c][r], w2pb[c]);
                    uint32 key = (__float_as_uint(s) & 0xFFFFFFC0u) | (uint32)((it << 2) | c);
                    uint32 mx = r1[ti] > key ? r1[ti] : key;
                    r1[ti] = r1[ti] < key ? r1[ti] : key;
                    r2[ti] = r2[ti] < mx ? r2[ti] : mx;
                }
            }
        wit += (size_t)256 * DIM;
    }

    // ------- merge: all 128 entries per token via LDS, two phases by wt -----
    u64* MS = (u64*)POOL;   // 64 tokens x 128 entries = 64 KiB
    for (int phase = 0; phase < 2; ++phase) {
        __syncthreads();
        if (wt == phase) {
            #pragma unroll
            for (int ti = 0; ti < 16; ++ti) {
                const int i = ti >> 2, r = ti & 3;
                const int tloc = i * 16 + quad * 4 + r;     // 0..63
                #pragma unroll
                for (int e = 0; e < 2; ++e) {
                    uint32 k  = e ? r2[ti] : r1[ti];
                    uint32 vb = k & 0xFFFFFFC0u;
                    uint32 id = k & 63u;
                    uint32 code = (uint32)(sbase + (id >> 2) * 256 + wc * 64 + (id & 3) * 16 + n15);
                    MS[tloc * 128 + (wc * 16 + n15) * 2 + e] = ((u64)vb << 32) | code;
                }
            }
        }
        __syncthreads();
        if (tid < 64) {
            u64 best[6];
            #pragma unroll
            for (int c = 0; c < 6; ++c) best[c] = 0xFFFFFFFFFFFFFFFFull;
            for (int e = 0; e < 128; ++e) {
                u64 v = MS[tid * 128 + e];
                if (v < best[5]) {
                    best[5] = v;
                    #pragma unroll
                    for (int p = 5; p > 0; --p)
                        if (best[p] < best[p - 1]) { u64 tv = best[p]; best[p] = best[p - 1]; best[p - 1] = tv; }
                }
            }
            const int token = m0 + phase * 64 + tid;
            u64* dst = candPart + ((size_t)blockIdx.y * N_TOK + token) * 6;
            #pragma unroll
            for (int c = 0; c < 6; ++c) dst[c] = best[c];
        }
    }
}

// ---------------------------------------------------------------------------
// Merge per-split top-6 lists -> global top-NCAND candidate codes per token.
// ---------------------------------------------------------------------------
__global__ __launch_bounds__(256) void mergecand_kernel(const u64* __restrict__ candPart,
                                                        int* __restrict__ candF) {
    int t = blockIdx.x * 256 + threadIdx.x;
    u64 best[NCAND];
    #pragma unroll
    for (int c = 0; c < NCAND; ++c) best[c] = 0xFFFFFFFFFFFFFFFFull;
    for (int s = 0; s < NSPLIT; ++s) {
        const u64* src = candPart + ((size_t)s * N_TOK + t) * 6;
        #pragma unroll
        for (int c = 0; c < 6; ++c) {
            u64 v = src[c];
            if (v < best[NCAND - 1]) {
                best[NCAND - 1] = v;
                #pragma unroll
                for (int p = NCAND - 1; p > 0; --p)
                    if (best[p] < best[p - 1]) { u64 tv = best[p]; best[p] = best[p - 1]; best[p - 1] = tv; }
            }
        }
    }
    #pragma unroll
    for (int c = 0; c < NCAND; ++c) candF[(size_t)t * NCAND + c] = (int)(best[c] & 0xFFFu);
}

// ---------------------------------------------------------------------------
// np-exact refine over NCAND candidates (R3-verified arithmetic).
// ---------------------------------------------------------------------------
__global__ __launch_bounds__(256) void refine_kernel(const float* __restrict__ x,
                                                     const float* __restrict__ w,
                                                     const float* __restrict__ x2np,
                                                     const float* __restrict__ w2np,
                                                     const int* __restrict__ cand,
                                                     int* __restrict__ idx) {
    const int t    = blockIdx.x * 4 + (threadIdx.x >> 6);
    const int lane = threadIdx.x & 63;

    const float* xr = x + (size_t)t * DIM;
    float xv[8];
    #pragma unroll
    for (int j = 0; j < 8; ++j) xv[j] = xr[lane + 64 * j];
    const float x2 = x2np[t];

    float bd = 3.4e38f;
    int   bk = 0x7fffffff;
    for (int c = 0; c < NCAND; ++c) {
        int k = cand[(size_t)t * NCAND + c];
        const float* wr = w + (size_t)k * DIM;
        double m = 0.0;
        #pragma unroll
        for (int j = 0; j < 8; ++j)
            m = fma((double)xv[j], (double)wr[lane + 64 * j], m);
        #pragma unroll
        for (int off = 32; off >= 1; off >>= 1) m += __shfl_down(m, off);
        if (lane == 0) {
            #pragma clang fp contract(off)
            float m32 = (float)m;
            float T1  = x2 + w2np[k];
            float d   = T1 - 2.0f * m32;
            if (d < bd || (d == bd && k < bk)) { bd = d; bk = k; }
        }
    }
    if (lane == 0) idx[t] = bk;
}

// ---------------------------------------------------------------------------
// gather + straight-through output + loss + counts (R3-verified).
// ---------------------------------------------------------------------------
__global__ __launch_bounds__(256) void gather_kernel(const float* __restrict__ x,
                                                     const float* __restrict__ w,
                                                     const int* __restrict__ idx,
                                                     float* __restrict__ out_q,
                                                     float* __restrict__ out_loss,
                                                     float* __restrict__ out_ind,
                                                     int* __restrict__ counts) {
    const int wave = threadIdx.x >> 6;
    const int lane = threadIdx.x & 63;
    const int token = blockIdx.x * 4 + wave;
    const int k = idx[token];

    const float4* xr = (const float4*)(x + (size_t)token * DIM);
    const float4* wr = (const float4*)(w + (size_t)k * DIM);
    float4*       qo = (float4*)(out_q + (size_t)token * DIM);

    float ss = 0.f;
    #pragma unroll
    for (int j = 0; j < 2; ++j) {
        int e = lane + j * 64;
        float4 xv = xr[e];
        float4 wv = wr[e];
        float4 d, o;
        d.x = wv.x - xv.x; o.x = xv.x + d.x;
        d.y = wv.y - xv.y; o.y = xv.y + d.y;
        d.z = wv.z - xv.z; o.z = xv.z + d.z;
        d.w = wv.w - xv.w; o.w = xv.w + d.w;
        ss += d.x * d.x + d.y * d.y + d.z * d.z + d.w * d.w;
        qo[e] = o;
    }
    #pragma unroll
    for (int off = 32; off >= 1; off >>= 1) ss += __shfl_down(ss, off);
    if (lane == 0) {
        float lm = ss * (1.0f / DIM);
        out_loss[token] = lm + COMMIT * lm;
        out_ind[token] = (float)k;
        atomicAdd(&counts[k], 1);
    }
}

// ---------------------------------------------------------------------------
// perplexity (R3-verified).
// ---------------------------------------------------------------------------
__global__ __launch_bounds__(256) void perplex_kernel(const int* __restrict__ counts,
                                                      float* __restrict__ out2) {
    __shared__ double red[4];
    const int tid = threadIdx.x;
    const int lane = tid & 63;
    const int wid = tid >> 6;
    double s = 0.0;
    for (int t = tid; t < K_CODES; t += 256) {
        int c = counts[t];
        if (c) {
            double p = (double)c * (1.0 / N_TOK);
            s += p * log(p + 1e-10);
        }
    }
    #pragma unroll
    for (int off = 32; off >= 1; off >>= 1) s += __shfl_down(s, off);
    if (lane == 0) red[wid] = s;
    __syncthreads();
    if (tid == 0) {
        double t = red[0] + red[1] + red[2] + red[3];
        out2[0] = (float)exp(-t);
    }
}

// ---------------------------------------------------------------------------
extern "C" void kernel_launch(void* const* d_in, const int* in_sizes, int n_in,
                              void* d_out, int out_size, void* d_ws, size_t ws_size,
                              hipStream_t stream) {
    const float* x = (const float*)d_in[0];
    const float* w = (const float*)d_in[1];

    float* out0 = (float*)d_out;                       // quantized_st [N,D]
    float* out1 = out0 + (size_t)N_TOK * DIM;          // loss [N]
    float* out2 = out1 + N_TOK;                        // perplexity [1]
    float* out3 = out2 + 1;                            // indices [N] (as float)

    // workspace layout (8B-aligned chunks first)
    u64*   candPart = (u64*)d_ws;                                 // NSPLIT*N_TOK*6
    float* x2np     = (float*)(candPart + (size_t)NSPLIT * N_TOK * 6);
    float* w2np     = x2np + N_TOK;
    int*   idx      = (int*)(w2np + K_CODES);
    int*   counts   = idx + N_TOK;
    int*   candF    = counts + K_CODES;                           // N_TOK*NCAND
    u16*   x_bf     = (u16*)(candF + (size_t)N_TOK * NCAND);      // N_TOK*DIM
    u16*   w_bf     = x_bf + (size_t)N_TOK * DIM;                 // K_CODES*DIM

    hipMemsetAsync(counts, 0, K_CODES * sizeof(int), stream);

    tobf16_kernel<<<4096, 256, 0, stream>>>(x, x_bf, N_TOK * DIM / 4);
    tobf16_kernel<<<2048, 256, 0, stream>>>(w, w_bf, K_CODES * DIM / 4);
    rowsq_np_kernel<<<N_TOK / 32, 256, 0, stream>>>(x, x2np, N_TOK);
    rowsq_np_kernel<<<K_CODES / 32, 256, 0, stream>>>(w, w2np, K_CODES);
    screen_kernel<<<dim3(N_TOK / 128, NSPLIT), 512, 0, stream>>>(x_bf, w_bf, w2np, candPart);
    mergecand_kernel<<<N_TOK / 256, 256, 0, stream>>>(candPart, candF);
    refine_kernel<<<N_TOK / 4, 256, 0, stream>>>(x, w, x2np, w2np, candF, idx);
    gather_kernel<<<N_TOK / 4, 256, 0, stream>>>(x, w, idx, out0, out1, out3, counts);
    perplex_kernel<<<1, 256, 0, stream>>>(counts, out2);
}